// Round 1
// baseline (2907.102 us; speedup 1.0000x reference)
//
#include <hip/hip_runtime.h>
#include <hip/hip_bf16.h>
#include <math.h>

#define HH 128
#define WW 128
#define NFEAT 64
#define PLANE (HH*WW)

// ---------------------------------------------------------------------------
// Generic 3x3 conv, stride 1, pad 1 (zero), NCHW, optional leaky-relu(0.1).
// Input may be a virtual concat of two tensors x0 (C0 ch) and x1 (C1 ch).
// Each block: 16x16 output pixels, OC output channels.
// grid = (W/16, H/16, B * (Cout/OC))
// ---------------------------------------------------------------------------
template<int OC, bool LRELU>
__global__ __launch_bounds__(256)
void conv3x3_kernel(const float* __restrict__ x0, const float* __restrict__ x1,
                    int C0, int C1,
                    const float* __restrict__ w,     // [Cout][C0+C1][3][3]
                    const float* __restrict__ bias,  // [Cout]
                    float* __restrict__ out,         // [B][Cout][H][W]
                    int Cout)
{
    const int tx = threadIdx.x & 15;
    const int ty = threadIdx.x >> 4;
    const int tile_x = blockIdx.x * 16;
    const int tile_y = blockIdx.y * 16;
    const int nChunk = Cout / OC;
    const int b   = blockIdx.z / nChunk;
    const int oc0 = (blockIdx.z % nChunk) * OC;
    const int Cin = C0 + C1;

    __shared__ float smem[4][18 * 18];

    float acc[OC];
#pragma unroll
    for (int o = 0; o < OC; ++o) acc[o] = 0.f;

#pragma unroll 1
    for (int c0 = 0; c0 < Cin; c0 += 4) {
        __syncthreads();
        // stage 4 channels of the 18x18 halo tile
        for (int idx = threadIdx.x; idx < 4 * 18 * 18; idx += 256) {
            int ch = idx / 324;
            int r  = (idx - ch * 324) / 18;
            int cc = idx - ch * 324 - r * 18;
            int gy = tile_y + r - 1;
            int gx = tile_x + cc - 1;
            int c  = c0 + ch;
            float v = 0.f;
            if (gy >= 0 && gy < HH && gx >= 0 && gx < WW) {
                const float* src = (c < C0)
                    ? (x0 + ((size_t)(b * C0 + c)) * PLANE)
                    : (x1 + ((size_t)(b * C1 + (c - C0))) * PLANE);
                v = src[gy * WW + gx];
            }
            smem[ch][r * 18 + cc] = v;
        }
        __syncthreads();

#pragma unroll
        for (int ch = 0; ch < 4; ++ch) {
            const int c = c0 + ch;
            float in[9];
#pragma unroll
            for (int dy = 0; dy < 3; ++dy)
#pragma unroll
                for (int dx = 0; dx < 3; ++dx)
                    in[dy * 3 + dx] = smem[ch][(ty + dy) * 18 + tx + dx];

#pragma unroll
            for (int o = 0; o < OC; ++o) {
                // uniform address -> scalar loads
                const float* wo = w + ((size_t)(oc0 + o) * Cin + c) * 9;
#pragma unroll
                for (int k = 0; k < 9; ++k)
                    acc[o] = fmaf(wo[k], in[k], acc[o]);
            }
        }
    }

    const int y = tile_y + ty;
    const int x = tile_x + tx;
#pragma unroll
    for (int o = 0; o < OC; ++o) {
        float v = acc[o] + bias[oc0 + o];
        if (LRELU) v = (v >= 0.f) ? v : 0.1f * v;
        out[(((size_t)b * Cout + oc0 + o) * HH + y) * WW + x] = v;
    }
}

// ---------------------------------------------------------------------------
// Repack dcn weights [O=64][I=64][3][3] -> [g][k2][c][o] (contiguous in o)
// ---------------------------------------------------------------------------
__global__ void repack_dcn_w_kernel(const float* __restrict__ w,
                                    float* __restrict__ wr)
{
    int idx = blockIdx.x * 256 + threadIdx.x;   // ((g*9+k2)*8+c)*64+o
    if (idx >= 8 * 9 * 8 * 64) return;
    int o    = idx & 63;
    int rest = idx >> 6;
    int c    = rest & 7;
    int gk   = rest >> 3;
    int k2   = gk % 9;
    int g    = gk / 9;
    wr[idx] = w[((size_t)(o * 64 + g * 8 + c)) * 9 + k2];
}

// ---------------------------------------------------------------------------
// Modulated deformable conv v2 (3x3, pad 1, DG=8 offset groups, conv groups=1)
// fea: [B,64,H,W]; om (raw conv_offset_mask output): [B,216,H,W]
// channel map per (g,k2): dy = g*18+2*k2, dx = g*18+2*k2+1, mask = 144+g*9+k2
// wr: repacked weights [g][k2][c][o]. Output gets leaky-relu(0.1).
// grid = (W/16, H/16, B), block = 256 (one pixel per thread)
// ---------------------------------------------------------------------------
__global__ __launch_bounds__(256)
void dcn_kernel(const float* __restrict__ fea,
                const float* __restrict__ om,
                const float* __restrict__ wr,
                const float* __restrict__ bias,
                float* __restrict__ out)
{
    const int tx = threadIdx.x & 15;
    const int ty = threadIdx.x >> 4;
    const int x  = blockIdx.x * 16 + tx;
    const int y  = blockIdx.y * 16 + ty;
    const int b  = blockIdx.z;

    float acc[64];
#pragma unroll
    for (int o = 0; o < 64; ++o) acc[o] = 0.f;

    const float* omb = om + (size_t)b * 216 * PLANE + y * WW + x;

#pragma unroll 1
    for (int g = 0; g < 8; ++g) {
        const float* feag = fea + ((size_t)b * NFEAT + g * 8) * PLANE;
#pragma unroll 1
        for (int k2 = 0; k2 < 9; ++k2) {
            const int kyi = k2 / 3;
            const int kxi = k2 - kyi * 3;
            float dy = omb[(size_t)(g * 18 + 2 * k2) * PLANE];
            float dx = omb[(size_t)(g * 18 + 2 * k2 + 1) * PLANE];
            float mk = omb[(size_t)(144 + g * 9 + k2) * PLANE];
            mk = 1.f / (1.f + expf(-mk));

            float py = (float)(y + kyi - 1) + dy;
            float px = (float)(x + kxi - 1) + dx;
            float fy = floorf(py), fx = floorf(px);
            int   y0 = (int)fy,    x0 = (int)fx;
            float ly = py - fy,    lx = px - fx;
            int   y1 = y0 + 1,     x1 = x0 + 1;

            float vy0 = (y0 >= 0 && y0 < HH) ? 1.f : 0.f;
            float vy1 = (y1 >= 0 && y1 < HH) ? 1.f : 0.f;
            float vx0 = (x0 >= 0 && x0 < WW) ? 1.f : 0.f;
            float vx1 = (x1 >= 0 && x1 < WW) ? 1.f : 0.f;

            float w00 = (1.f - ly) * (1.f - lx) * vy0 * vx0 * mk;
            float w01 = (1.f - ly) * lx         * vy0 * vx1 * mk;
            float w10 = ly         * (1.f - lx) * vy1 * vx0 * mk;
            float w11 = ly         * lx         * vy1 * vx1 * mk;

            int cy0 = min(max(y0, 0), HH - 1);
            int cy1 = min(max(y1, 0), HH - 1);
            int cx0 = min(max(x0, 0), WW - 1);
            int cx1 = min(max(x1, 0), WW - 1);
            int i00 = cy0 * WW + cx0;
            int i01 = cy0 * WW + cx1;
            int i10 = cy1 * WW + cx0;
            int i11 = cy1 * WW + cx1;

            const float* wgk = wr + ((size_t)(g * 9 + k2) * 8) * 64;
#pragma unroll
            for (int c = 0; c < 8; ++c) {
                const float* fp = feag + (size_t)c * PLANE;
                float v = w00 * fp[i00] + w01 * fp[i01]
                        + w10 * fp[i10] + w11 * fp[i11];
                const float* wc = wgk + c * 64;   // uniform -> s_load
#pragma unroll
                for (int o = 0; o < 64; ++o)
                    acc[o] = fmaf(wc[o], v, acc[o]);
            }
        }
    }

#pragma unroll
    for (int o = 0; o < 64; ++o) {
        float v = acc[o] + bias[o];
        v = (v >= 0.f) ? v : 0.1f * v;
        out[(((size_t)b * NFEAT + o) * HH + y) * WW + x] = v;
    }
}

// ---------------------------------------------------------------------------
extern "C" void kernel_launch(void* const* d_in, const int* in_sizes, int n_in,
                              void* d_out, int out_size, void* d_ws, size_t ws_size,
                              hipStream_t stream) {
    const float* fea      = (const float*)d_in[0];
    const float* ref      = (const float*)d_in[1];
    const float* w_of1    = (const float*)d_in[2];
    const float* b_of1    = (const float*)d_in[3];
    const float* w_of2    = (const float*)d_in[4];
    const float* b_of2    = (const float*)d_in[5];
    const float* w_or1    = (const float*)d_in[6];
    const float* b_or1    = (const float*)d_in[7];
    const float* w_or2    = (const float*)d_in[8];
    const float* b_or2    = (const float*)d_in[9];
    const float* w_om     = (const float*)d_in[10];
    const float* b_om     = (const float*)d_in[11];
    const float* w_dcn    = (const float*)d_in[12];
    const float* b_dcn    = (const float*)d_in[13];
    const float* w_fu1    = (const float*)d_in[14];
    const float* b_fu1    = (const float*)d_in[15];
    const float* w_fu2    = (const float*)d_in[16];
    const float* b_fu2    = (const float*)d_in[17];

    const int B = 4;
    const size_t featN = (size_t)B * NFEAT * PLANE;       // 4,194,304
    const size_t omN   = (size_t)B * 216 * PLANE;         // 14,155,776

    float* of1  = (float*)d_ws;
    float* om   = of1  + featN;
    float* dfea = om   + omN;
    float* dref = dfea + featN;
    float* wrep = dref + featN;                           // 36,864 floats
    float* of2  = (float*)d_out;                          // reuse output as scratch

    dim3 blk(256, 1, 1);
    dim3 gConv16(WW / 16, HH / 16, B * (NFEAT / 16));     // OC=16, Cout=64
    dim3 gConvOM(WW / 16, HH / 16, B * (216 / 8));        // OC=8,  Cout=216
    dim3 gDcn(WW / 16, HH / 16, B);

    // repack dcn weights once (cheap, stream-ordered)
    repack_dcn_w_kernel<<<(8 * 9 * 8 * 64 + 255) / 256, blk, 0, stream>>>(w_dcn, wrep);

    // ---- branch 1: fea_l ----
    conv3x3_kernel<16, true ><<<gConv16, blk, 0, stream>>>(fea, ref, 64, 64, w_of1, b_of1, of1, 64);
    conv3x3_kernel<16, true ><<<gConv16, blk, 0, stream>>>(of1, nullptr, 64, 0, w_of2, b_of2, of2, 64);
    conv3x3_kernel<8,  false><<<gConvOM, blk, 0, stream>>>(of2, nullptr, 64, 0, w_om, b_om, om, 216);
    dcn_kernel<<<gDcn, blk, 0, stream>>>(fea, om, wrep, b_dcn, dfea);

    // ---- branch 2: ref_fea_l ----
    conv3x3_kernel<16, true ><<<gConv16, blk, 0, stream>>>(ref, fea, 64, 64, w_or1, b_or1, of1, 64);
    conv3x3_kernel<16, true ><<<gConv16, blk, 0, stream>>>(of1, nullptr, 64, 0, w_or2, b_or2, of2, 64);
    conv3x3_kernel<8,  false><<<gConvOM, blk, 0, stream>>>(of2, nullptr, 64, 0, w_om, b_om, om, 216);
    dcn_kernel<<<gDcn, blk, 0, stream>>>(ref, om, wrep, b_dcn, dref);

    // ---- fusion ----
    conv3x3_kernel<16, true ><<<gConv16, blk, 0, stream>>>(dfea, dref, 64, 64, w_fu1, b_fu1, of1, 64);
    conv3x3_kernel<16, true ><<<gConv16, blk, 0, stream>>>(of1, nullptr, 64, 0, w_fu2, b_fu2, (float*)d_out, 64);

    (void)in_sizes; (void)n_in; (void)out_size; (void)ws_size;
}

// Round 3
// 829.984 us; speedup vs baseline: 3.5026x; 3.5026x over previous
//
#include <hip/hip_runtime.h>
#include <hip/hip_fp16.h>
#include <math.h>

#define HH 128
#define WW 128
#define PLANE (HH*WW)
#define BB 4

typedef _Float16 f16x8 __attribute__((ext_vector_type(8)));
typedef float f32x4 __attribute__((ext_vector_type(4)));

__device__ __forceinline__ float lrelu(float v) { return v >= 0.f ? v : 0.1f * v; }

__device__ __forceinline__ uint32_t pack2h(float a, float b) {
    return (uint32_t)__half_as_ushort(__float2half(b)) << 16 |
           (uint32_t)__half_as_ushort(__float2half(a));
}

// ---------------------------------------------------------------------------
// NCHW fp32 (64ch) -> NHWC fp16 convert.  grid = B*H*W/256
// ---------------------------------------------------------------------------
__global__ __launch_bounds__(256)
void convert_kernel(const float* __restrict__ in, __half* __restrict__ out)
{
    int pix = blockIdx.x * 256 + threadIdx.x;  // b*16384 + y*128 + x
    int b = pix >> 14;
    int p = pix & 16383;
    const float* src = in + (size_t)b * 64 * PLANE + p;
    uint32_t buf[32];
#pragma unroll
    for (int c = 0; c < 64; c += 2)
        buf[c >> 1] = pack2h(src[(size_t)c * PLANE], src[(size_t)(c + 1) * PLANE]);
    uint4* dst = (uint4*)(out + (size_t)pix * 64);
#pragma unroll
    for (int i = 0; i < 8; ++i)
        dst[i] = make_uint4(buf[4*i], buf[4*i+1], buf[4*i+2], buf[4*i+3]);
}

// ---------------------------------------------------------------------------
// Repack conv weights fp32 [Cout][Cin][3][3] -> fp16 [cc][tap][OPAD][32]
// o >= Cout zero-padded.
// ---------------------------------------------------------------------------
__global__ __launch_bounds__(256)
void repack_w16_kernel(const float* __restrict__ src, __half* __restrict__ dst,
                       int Cout, int Cin, int OPAD)
{
    int idx = blockIdx.x * 256 + threadIdx.x;
    int total = Cin * 9 * OPAD;
    if (idx >= total) return;
    int cp   = idx & 31;
    int o    = (idx >> 5) % OPAD;
    int rest = idx / (32 * OPAD);
    int tap  = rest % 9;
    int cc   = rest / 9;
    int c = cc * 32 + cp;
    float v = (o < Cout) ? src[((size_t)o * Cin + c) * 9 + tap] : 0.f;
    dst[idx] = __float2half(v);
}

// ---------------------------------------------------------------------------
// Repack dcn weights [O=64][I=64][3][3] -> fp32 [g][k2][c][o]
// ---------------------------------------------------------------------------
__global__ void repack_dcn_w_kernel(const float* __restrict__ w,
                                    float* __restrict__ wr)
{
    int idx = blockIdx.x * 256 + threadIdx.x;   // ((g*9+k2)*8+c)*64+o
    if (idx >= 8 * 9 * 8 * 64) return;
    int o    = idx & 63;
    int rest = idx >> 6;
    int c    = rest & 7;
    int gk   = rest >> 3;
    int k2   = gk % 9;
    int g    = gk / 9;
    wr[idx] = w[((size_t)(o * 64 + g * 8 + c)) * 9 + k2];
}

// ---------------------------------------------------------------------------
// MFMA implicit-GEMM 3x3 conv, stride 1, pad 1, fp16 in (NHWC, C=64 per
// tensor, concat via x0/x1), fp32 accumulate.
// KG = Cin/32 (2 or 4); CHUNKS = OPAD/64; OUTMODE: 0 = NHWC fp16 + lrelu,
// 1 = NCHW(stride 224) fp16 raw (om), 2 = NCHW fp32 + lrelu (final out).
// Block: 256 thr / 4 waves; tile 16x16 px, 64 out-ch. Each wave: 4 Mtiles x
// 4 Ntiles (rows 4w..4w+3) of 16x16x32 MFMA.
// grid = (8, 8, jobs*CHUNKS*B), job pairs batched via z.
// ---------------------------------------------------------------------------
template<int KG, int CHUNKS, int OUTMODE>
__global__ __launch_bounds__(256, 4)
void conv_mfma_kernel(const __half* __restrict__ x0a, const __half* __restrict__ x1a,
                      const __half* __restrict__ x0b, const __half* __restrict__ x1b,
                      const __half* __restrict__ wa,  const __half* __restrict__ wb,
                      const float* __restrict__ ba,   const float* __restrict__ bb,
                      void* __restrict__ outa, void* __restrict__ outb,
                      int CoutReal)
{
    constexpr int OPAD = CHUNKS * 64;
    const int tid  = threadIdx.x;
    const int lane = tid & 63;
    const int wv   = tid >> 6;
    const int p16  = lane & 15;
    const int q    = lane >> 4;

    const int zz    = blockIdx.z;
    const int job   = zz / (BB * CHUNKS);
    const int rem   = zz % (BB * CHUNKS);
    const int chunk = rem / BB;
    const int b     = rem % BB;
    const int oc0   = chunk * 64;
    const int tx0   = blockIdx.x * 16;
    const int ty0   = blockIdx.y * 16;

    const __half* x0  = job ? x0b : x0a;
    const __half* x1  = job ? x1b : x1a;
    const __half* wr  = job ? wb  : wa;
    const float* bias = job ? bb  : ba;
    void* outp        = job ? outb : outa;

    // act: 18x18 halo, 32ch per K-group, c-stride padded to 40 halfs (80 B,
    // 16B-aligned, bank-balanced for b128 reads).  weights: double-buffered.
    __shared__ __align__(16) __half act[18 * 18 * 40];
    __shared__ __align__(16) __half wl[2][64 * 40];

    f32x4 acc[4][4];
#pragma unroll
    for (int mt = 0; mt < 4; ++mt)
#pragma unroll
        for (int nt = 0; nt < 4; ++nt)
            acc[mt][nt] = (f32x4)(0.f);

    const int wo  = tid >> 2;       // weight-stage: o-row
    const int wqq = tid & 3;        // weight-stage: 8-half chunk

#pragma unroll 1
    for (int kg = 0; kg < KG; ++kg) {
        // ---- stage activation K-group (32 ch) into halo tile ----
        {
            const __half* src = (KG == 4 && kg >= 2) ? x1 : x0;
            const int csel = (KG == 4) ? (kg & 1) : kg;
#pragma unroll
            for (int i = 0; i < 6; ++i) {
                int t = tid + i * 256;
                if (t < 1296) {             // 324 px * 4 chunks
                    int pix = t >> 2, qq = t & 3;
                    int ry = pix / 18, cx = pix - ry * 18;
                    int y = ty0 + ry - 1, x = tx0 + cx - 1;
                    uint4 v = make_uint4(0, 0, 0, 0);
                    if ((unsigned)y < HH && (unsigned)x < WW)
                        v = *(const uint4*)(src + ((size_t)((b * HH + y) * WW + x)) * 64
                                            + csel * 32 + qq * 8);
                    *(uint4*)(&act[pix * 40 + qq * 8]) = v;
                }
            }
        }
        if (kg == 0) {
            uint4 v = *(const uint4*)(wr + ((size_t)(oc0 + wo)) * 32 + wqq * 8);
            *(uint4*)(&wl[0][wo * 40 + wqq * 8]) = v;
        }
        __syncthreads();

#pragma unroll
        for (int tap = 0; tap < 9; ++tap) {
            const int step = kg * 9 + tap;
            const int cur = step & 1;
            // prefetch next tap's weights into other buffer
            if (step + 1 < KG * 9) {
                int ntap = (tap + 1) % 9;
                int nkg  = kg + (tap == 8 ? 1 : 0);
                uint4 v = *(const uint4*)(wr + ((size_t)((nkg * 9 + ntap) * OPAD + oc0 + wo)) * 32
                                          + wqq * 8);
                *(uint4*)(&wl[cur ^ 1][wo * 40 + wqq * 8]) = v;
            }
            const int dy = tap / 3, dx = tap % 3;
            f16x8 af[4];
#pragma unroll
            for (int mt = 0; mt < 4; ++mt)
                af[mt] = *(const f16x8*)(&wl[cur][(mt * 16 + p16) * 40 + q * 8]);
#pragma unroll
            for (int nt = 0; nt < 4; ++nt) {
                int ry = 4 * wv + nt + dy;
                int cx = p16 + dx;
                f16x8 bf = *(const f16x8*)(&act[(ry * 18 + cx) * 40 + q * 8]);
#pragma unroll
                for (int mt = 0; mt < 4; ++mt)
                    acc[mt][nt] = __builtin_amdgcn_mfma_f32_16x16x32_f16(
                        af[mt], bf, acc[mt][nt], 0, 0, 0);
            }
            __syncthreads();
        }
    }

    // ---- epilogue ----
    float bv[4][4];
#pragma unroll
    for (int mt = 0; mt < 4; ++mt)
#pragma unroll
        for (int r = 0; r < 4; ++r) {
            int o = oc0 + mt * 16 + q * 4 + r;
            bv[mt][r] = (o < CoutReal) ? bias[o] : 0.f;
        }

    const int xg = tx0 + p16;
#pragma unroll
    for (int nt = 0; nt < 4; ++nt) {
        int yg = ty0 + 4 * wv + nt;
        if (OUTMODE == 0) {
            __half* op = (__half*)outp + ((size_t)((b * HH + yg) * WW + xg)) * 64;
#pragma unroll
            for (int mt = 0; mt < 4; ++mt) {
                float v0 = lrelu(acc[mt][nt][0] + bv[mt][0]);
                float v1 = lrelu(acc[mt][nt][1] + bv[mt][1]);
                float v2 = lrelu(acc[mt][nt][2] + bv[mt][2]);
                float v3 = lrelu(acc[mt][nt][3] + bv[mt][3]);
                uint2 u = make_uint2(pack2h(v0, v1), pack2h(v2, v3));
                *(uint2*)(op + mt * 16 + q * 4) = u;
            }
        } else if (OUTMODE == 1) {
            __half* op = (__half*)outp + (size_t)b * 224 * PLANE + yg * WW + xg;
#pragma unroll
            for (int mt = 0; mt < 4; ++mt)
#pragma unroll
                for (int r = 0; r < 4; ++r) {
                    int o = oc0 + mt * 16 + q * 4 + r;
                    if (o < 224)
                        op[(size_t)o * PLANE] = __float2half(acc[mt][nt][r] + bv[mt][r]);
                }
        } else {
            float* op = (float*)outp + ((size_t)(b * 64) * HH) * WW + yg * WW + xg;
#pragma unroll
            for (int mt = 0; mt < 4; ++mt)
#pragma unroll
                for (int r = 0; r < 4; ++r) {
                    int o = mt * 16 + q * 4 + r;
                    op[(size_t)o * PLANE] = lrelu(acc[mt][nt][r] + bv[mt][r]);
                }
        }
    }
}

// ---------------------------------------------------------------------------
// Modulated deformable conv v2 (fp32 math). fea: fp32 NCHW input; om: fp16
// NCHW stride 224; out: NHWC fp16 with lrelu. Job pair via blockIdx.z.
// grid = (8, 8, 2*B), block 256 (one pixel per thread).
// ---------------------------------------------------------------------------
__global__ __launch_bounds__(256)
void dcn_kernel(const float* __restrict__ fa, const float* __restrict__ fb,
                const __half* __restrict__ oma, const __half* __restrict__ omb2,
                const float* __restrict__ wr, const float* __restrict__ bias,
                __half* __restrict__ outa, __half* __restrict__ outb)
{
    const int tx = threadIdx.x & 15;
    const int ty = threadIdx.x >> 4;
    const int x  = blockIdx.x * 16 + tx;
    const int y  = blockIdx.y * 16 + ty;
    const int job = blockIdx.z >> 2;
    const int b   = blockIdx.z & 3;

    const float*  fea = job ? fb : fa;
    const __half* om  = job ? omb2 : oma;
    __half*       out = job ? outb : outa;

    float acc[64];
#pragma unroll
    for (int o = 0; o < 64; ++o) acc[o] = 0.f;

    const __half* omb = om + (size_t)b * 224 * PLANE + y * WW + x;

#pragma unroll 1
    for (int g = 0; g < 8; ++g) {
        const float* feag = fea + ((size_t)b * 64 + g * 8) * PLANE;
#pragma unroll 1
        for (int k2 = 0; k2 < 9; ++k2) {
            const int kyi = k2 / 3;
            const int kxi = k2 - kyi * 3;
            float dy = __half2float(omb[(size_t)(g * 18 + 2 * k2) * PLANE]);
            float dx = __half2float(omb[(size_t)(g * 18 + 2 * k2 + 1) * PLANE]);
            float mk = __half2float(omb[(size_t)(144 + g * 9 + k2) * PLANE]);
            mk = 1.f / (1.f + expf(-mk));

            float py = (float)(y + kyi - 1) + dy;
            float px = (float)(x + kxi - 1) + dx;
            float fy = floorf(py), fx = floorf(px);
            int   y0 = (int)fy,    x0 = (int)fx;
            float ly = py - fy,    lx = px - fx;
            int   y1 = y0 + 1,     x1 = x0 + 1;

            float vy0 = (y0 >= 0 && y0 < HH) ? 1.f : 0.f;
            float vy1 = (y1 >= 0 && y1 < HH) ? 1.f : 0.f;
            float vx0 = (x0 >= 0 && x0 < WW) ? 1.f : 0.f;
            float vx1 = (x1 >= 0 && x1 < WW) ? 1.f : 0.f;

            float w00 = (1.f - ly) * (1.f - lx) * vy0 * vx0 * mk;
            float w01 = (1.f - ly) * lx         * vy0 * vx1 * mk;
            float w10 = ly         * (1.f - lx) * vy1 * vx0 * mk;
            float w11 = ly         * lx         * vy1 * vx1 * mk;

            int cy0 = min(max(y0, 0), HH - 1);
            int cy1 = min(max(y1, 0), HH - 1);
            int cx0 = min(max(x0, 0), WW - 1);
            int cx1 = min(max(x1, 0), WW - 1);
            int i00 = cy0 * WW + cx0;
            int i01 = cy0 * WW + cx1;
            int i10 = cy1 * WW + cx0;
            int i11 = cy1 * WW + cx1;

            const float* wgk = wr + ((size_t)(g * 9 + k2) * 8) * 64;
#pragma unroll
            for (int c = 0; c < 8; ++c) {
                const float* fp = feag + (size_t)c * PLANE;
                float v = w00 * fp[i00] + w01 * fp[i01]
                        + w10 * fp[i10] + w11 * fp[i11];
                const float* wc = wgk + c * 64;   // uniform -> scalar loads
#pragma unroll
                for (int o = 0; o < 64; ++o)
                    acc[o] = fmaf(wc[o], v, acc[o]);
            }
        }
    }

    uint32_t ob[32];
#pragma unroll
    for (int o = 0; o < 64; o += 2) {
        float v0 = lrelu(acc[o]     + bias[o]);
        float v1 = lrelu(acc[o + 1] + bias[o + 1]);
        ob[o >> 1] = pack2h(v0, v1);
    }
    uint4* dst = (uint4*)(out + ((size_t)((b * HH + y) * WW + x)) * 64);
#pragma unroll
    for (int i = 0; i < 8; ++i)
        dst[i] = make_uint4(ob[4*i], ob[4*i+1], ob[4*i+2], ob[4*i+3]);
}

// ---------------------------------------------------------------------------
extern "C" void kernel_launch(void* const* d_in, const int* in_sizes, int n_in,
                              void* d_out, int out_size, void* d_ws, size_t ws_size,
                              hipStream_t stream) {
    const float* fea   = (const float*)d_in[0];
    const float* ref   = (const float*)d_in[1];
    const float* w_of1 = (const float*)d_in[2];
    const float* b_of1 = (const float*)d_in[3];
    const float* w_of2 = (const float*)d_in[4];
    const float* b_of2 = (const float*)d_in[5];
    const float* w_or1 = (const float*)d_in[6];
    const float* b_or1 = (const float*)d_in[7];
    const float* w_or2 = (const float*)d_in[8];
    const float* b_or2 = (const float*)d_in[9];
    const float* w_om  = (const float*)d_in[10];
    const float* b_om  = (const float*)d_in[11];
    const float* w_dcn = (const float*)d_in[12];
    const float* b_dcn = (const float*)d_in[13];
    const float* w_fu1 = (const float*)d_in[14];
    const float* b_fu1 = (const float*)d_in[15];
    const float* w_fu2 = (const float*)d_in[16];
    const float* b_fu2 = (const float*)d_in[17];

    char* ws = (char*)d_ws;
    // activation slots: B*H*W*64 fp16 = 8,388,608 B each
    __half* S0 = (__half*)(ws);
    __half* S1 = (__half*)(ws + 8388608);
    __half* S2 = (__half*)(ws + 16777216);
    __half* S3 = (__half*)(ws + 25165824);
    // om tensors: B*224*PLANE fp16 = 29,360,128 B each
    __half* OMa = (__half*)(ws + 33554432);
    __half* OMb = (__half*)(ws + 62914560);
    // repacked weights
    size_t WB = 92274688;
    __half* W0 = (__half*)(ws + WB);            // of1a: 73728 h
    __half* W1 = (__half*)(ws + WB + 147456);   // of1b
    __half* W2 = (__half*)(ws + WB + 294912);   // of2a: 36864 h
    __half* W3 = (__half*)(ws + WB + 368640);   // of2b
    __half* W4 = (__half*)(ws + WB + 442368);   // om: 147456 h
    __half* W5 = (__half*)(ws + WB + 737280);   // fu1: 73728 h
    __half* W6 = (__half*)(ws + WB + 884736);   // fu2: 36864 h
    float*  W7 = (float*) (ws + WB + 958464);   // dcn fp32: 36864 f

    dim3 blk(256, 1, 1);

    // converts + repacks
    convert_kernel<<<256, blk, 0, stream>>>(fea, S0);
    convert_kernel<<<256, blk, 0, stream>>>(ref, S1);
    repack_w16_kernel<<<288, blk, 0, stream>>>(w_of1, W0, 64, 128, 64);
    repack_w16_kernel<<<288, blk, 0, stream>>>(w_or1, W1, 64, 128, 64);
    repack_w16_kernel<<<144, blk, 0, stream>>>(w_of2, W2, 64, 64, 64);
    repack_w16_kernel<<<144, blk, 0, stream>>>(w_or2, W3, 64, 64, 64);
    repack_w16_kernel<<<576, blk, 0, stream>>>(w_om,  W4, 216, 64, 256);
    repack_w16_kernel<<<288, blk, 0, stream>>>(w_fu1, W5, 64, 128, 64);
    repack_w16_kernel<<<144, blk, 0, stream>>>(w_fu2, W6, 64, 64, 64);
    repack_dcn_w_kernel<<<144, blk, 0, stream>>>(w_dcn, W7);

    // of1 pair: [fea||ref] and [ref||fea] -> S2, S3
    conv_mfma_kernel<4, 1, 0><<<dim3(8, 8, 8), blk, 0, stream>>>(
        S0, S1, S1, S0, W0, W1, b_of1, b_or1, S2, S3, 64);
    // of2 pair: S2 -> S0, S3 -> S1
    conv_mfma_kernel<2, 1, 0><<<dim3(8, 8, 8), blk, 0, stream>>>(
        S2, S2, S3, S3, W2, W3, b_of2, b_or2, S0, S1, 64);
    // om pair: S0 -> OMa, S1 -> OMb (shared weights/bias, raw fp16 NCHW-224)
    conv_mfma_kernel<2, 4, 1><<<dim3(8, 8, 32), blk, 0, stream>>>(
        S0, S0, S1, S1, W4, W4, b_om, b_om, OMa, OMb, 216);
    // dcn pair: (fea, OMa) -> S2, (ref, OMb) -> S3
    dcn_kernel<<<dim3(8, 8, 8), blk, 0, stream>>>(
        fea, ref, OMa, OMb, W7, b_dcn, S2, S3);
    // fuse1: [S2||S3] -> S0
    conv_mfma_kernel<4, 1, 0><<<dim3(8, 8, 4), blk, 0, stream>>>(
        S2, S3, S2, S3, W5, W5, b_fu1, b_fu1, S0, S0, 64);
    // fuse2: S0 -> d_out (fp32 NCHW + lrelu)
    conv_mfma_kernel<2, 1, 2><<<dim3(8, 8, 4), blk, 0, stream>>>(
        S0, S0, S0, S0, W6, W6, b_fu2, b_fu2, d_out, d_out, 64);

    (void)in_sizes; (void)n_in; (void)out_size; (void)ws_size;
}

// Round 4
// 459.490 us; speedup vs baseline: 6.3268x; 1.8063x over previous
//
#include <hip/hip_runtime.h>
#include <hip/hip_fp16.h>
#include <math.h>

#define HH 128
#define WW 128
#define PLANE (HH*WW)
#define BB 4

typedef _Float16 f16x8 __attribute__((ext_vector_type(8)));
typedef float f32x4 __attribute__((ext_vector_type(4)));

__device__ __forceinline__ float lrelu(float v) { return v >= 0.f ? v : 0.1f * v; }

__device__ __forceinline__ uint32_t pack2h(float a, float b) {
    return (uint32_t)__half_as_ushort(__float2half(b)) << 16 |
           (uint32_t)__half_as_ushort(__float2half(a));
}

// ---------------------------------------------------------------------------
// NCHW fp32 (64ch) -> NHWC fp16 convert.  grid = B*H*W/256
// ---------------------------------------------------------------------------
__global__ __launch_bounds__(256)
void convert_kernel(const float* __restrict__ in, __half* __restrict__ out)
{
    int pix = blockIdx.x * 256 + threadIdx.x;  // b*16384 + y*128 + x
    int b = pix >> 14;
    int p = pix & 16383;
    const float* src = in + (size_t)b * 64 * PLANE + p;
    uint32_t buf[32];
#pragma unroll
    for (int c = 0; c < 64; c += 2)
        buf[c >> 1] = pack2h(src[(size_t)c * PLANE], src[(size_t)(c + 1) * PLANE]);
    uint4* dst = (uint4*)(out + (size_t)pix * 64);
#pragma unroll
    for (int i = 0; i < 8; ++i)
        dst[i] = make_uint4(buf[4*i], buf[4*i+1], buf[4*i+2], buf[4*i+3]);
}

// ---------------------------------------------------------------------------
// Repack conv weights fp32 [Cout][Cin][3][3] -> fp16 [cc][tap][OPAD][32]
// ---------------------------------------------------------------------------
__global__ __launch_bounds__(256)
void repack_w16_kernel(const float* __restrict__ src, __half* __restrict__ dst,
                       int Cout, int Cin, int OPAD)
{
    int idx = blockIdx.x * 256 + threadIdx.x;
    int total = Cin * 9 * OPAD;
    if (idx >= total) return;
    int cp   = idx & 31;
    int o    = (idx >> 5) % OPAD;
    int rest = idx / (32 * OPAD);
    int tap  = rest % 9;
    int cc   = rest / 9;
    int c = cc * 32 + cp;
    float v = (o < Cout) ? src[((size_t)o * Cin + c) * 9 + tap] : 0.f;
    dst[idx] = __float2half(v);
}

// ---------------------------------------------------------------------------
// Repack dcn weights [O=64][I=64][3][3] -> fp16 [cc=18][o=64][k=32]
// k = tl*8 + c, gk = cc*4+tl, g = gk/9, k2 = gk%9, input ch = g*8+c
// ---------------------------------------------------------------------------
__global__ void repack_dcn_w16_kernel(const float* __restrict__ w,
                                      __half* __restrict__ wr)
{
    int idx = blockIdx.x * 256 + threadIdx.x;
    if (idx >= 18 * 64 * 32) return;
    int k  = idx & 31;
    int o  = (idx >> 5) & 63;
    int cc = idx >> 11;
    int tl = k >> 3, c = k & 7;
    int gk = cc * 4 + tl;
    int g = gk / 9, k2 = gk - g * 9;
    wr[idx] = __float2half(w[((size_t)o * 64 + g * 8 + c) * 9 + k2]);
}

// ---------------------------------------------------------------------------
// MFMA implicit-GEMM 3x3 conv, stride 1, pad 1, fp16 NHWC in, fp32 acc.
// KG = Cin/32; CHUNKS = OPAD/64; OUTMODE: 0 = NHWC64 fp16 + lrelu,
// 1 = NHWC stride-216 fp16 raw (om), 2 = NCHW fp32 + lrelu (final out).
// ---------------------------------------------------------------------------
template<int KG, int CHUNKS, int OUTMODE>
__global__ __launch_bounds__(256, 4)
void conv_mfma_kernel(const __half* __restrict__ x0a, const __half* __restrict__ x1a,
                      const __half* __restrict__ x0b, const __half* __restrict__ x1b,
                      const __half* __restrict__ wa,  const __half* __restrict__ wb,
                      const float* __restrict__ ba,   const float* __restrict__ bb,
                      void* __restrict__ outa, void* __restrict__ outb,
                      int CoutReal)
{
    constexpr int OPAD = CHUNKS * 64;
    const int tid  = threadIdx.x;
    const int lane = tid & 63;
    const int wv   = tid >> 6;
    const int p16  = lane & 15;
    const int q    = lane >> 4;

    const int zz    = blockIdx.z;
    const int job   = zz / (BB * CHUNKS);
    const int rem   = zz % (BB * CHUNKS);
    const int chunk = rem / BB;
    const int b     = rem % BB;
    const int oc0   = chunk * 64;
    const int tx0   = blockIdx.x * 16;
    const int ty0   = blockIdx.y * 16;

    const __half* x0  = job ? x0b : x0a;
    const __half* x1  = job ? x1b : x1a;
    const __half* wr  = job ? wb  : wa;
    const float* bias = job ? bb  : ba;
    void* outp        = job ? outb : outa;

    __shared__ __align__(16) __half act[18 * 18 * 40];
    __shared__ __align__(16) __half wl[2][64 * 40];

    f32x4 acc[4][4];
#pragma unroll
    for (int mt = 0; mt < 4; ++mt)
#pragma unroll
        for (int nt = 0; nt < 4; ++nt)
            acc[mt][nt] = (f32x4)(0.f);

    const int wo  = tid >> 2;
    const int wqq = tid & 3;

#pragma unroll 1
    for (int kg = 0; kg < KG; ++kg) {
        {
            const __half* src = (KG == 4 && kg >= 2) ? x1 : x0;
            const int csel = (KG == 4) ? (kg & 1) : kg;
#pragma unroll
            for (int i = 0; i < 6; ++i) {
                int t = tid + i * 256;
                if (t < 1296) {
                    int pix = t >> 2, qq = t & 3;
                    int ry = pix / 18, cx = pix - ry * 18;
                    int y = ty0 + ry - 1, x = tx0 + cx - 1;
                    uint4 v = make_uint4(0, 0, 0, 0);
                    if ((unsigned)y < HH && (unsigned)x < WW)
                        v = *(const uint4*)(src + ((size_t)((b * HH + y) * WW + x)) * 64
                                            + csel * 32 + qq * 8);
                    *(uint4*)(&act[pix * 40 + qq * 8]) = v;
                }
            }
        }
        if (kg == 0) {
            uint4 v = *(const uint4*)(wr + ((size_t)(oc0 + wo)) * 32 + wqq * 8);
            *(uint4*)(&wl[0][wo * 40 + wqq * 8]) = v;
        }
        __syncthreads();

#pragma unroll
        for (int tap = 0; tap < 9; ++tap) {
            const int step = kg * 9 + tap;
            const int cur = step & 1;
            if (step + 1 < KG * 9) {
                int ntap = (tap + 1) % 9;
                int nkg  = kg + (tap == 8 ? 1 : 0);
                uint4 v = *(const uint4*)(wr + ((size_t)((nkg * 9 + ntap) * OPAD + oc0 + wo)) * 32
                                          + wqq * 8);
                *(uint4*)(&wl[cur ^ 1][wo * 40 + wqq * 8]) = v;
            }
            const int dy = tap / 3, dx = tap % 3;
            f16x8 af[4];
#pragma unroll
            for (int mt = 0; mt < 4; ++mt)
                af[mt] = *(const f16x8*)(&wl[cur][(mt * 16 + p16) * 40 + q * 8]);
#pragma unroll
            for (int nt = 0; nt < 4; ++nt) {
                int ry = 4 * wv + nt + dy;
                int cx = p16 + dx;
                f16x8 bf = *(const f16x8*)(&act[(ry * 18 + cx) * 40 + q * 8]);
#pragma unroll
                for (int mt = 0; mt < 4; ++mt)
                    acc[mt][nt] = __builtin_amdgcn_mfma_f32_16x16x32_f16(
                        af[mt], bf, acc[mt][nt], 0, 0, 0);
            }
            __syncthreads();
        }
    }

    float bv[4][4];
#pragma unroll
    for (int mt = 0; mt < 4; ++mt)
#pragma unroll
        for (int r = 0; r < 4; ++r) {
            int o = oc0 + mt * 16 + q * 4 + r;
            bv[mt][r] = (o < CoutReal) ? bias[o] : 0.f;
        }

    const int xg = tx0 + p16;
#pragma unroll
    for (int nt = 0; nt < 4; ++nt) {
        int yg = ty0 + 4 * wv + nt;
        if (OUTMODE == 0) {
            __half* op = (__half*)outp + ((size_t)((b * HH + yg) * WW + xg)) * 64;
#pragma unroll
            for (int mt = 0; mt < 4; ++mt) {
                float v0 = lrelu(acc[mt][nt][0] + bv[mt][0]);
                float v1 = lrelu(acc[mt][nt][1] + bv[mt][1]);
                float v2 = lrelu(acc[mt][nt][2] + bv[mt][2]);
                float v3 = lrelu(acc[mt][nt][3] + bv[mt][3]);
                *(uint2*)(op + mt * 16 + q * 4) = make_uint2(pack2h(v0, v1), pack2h(v2, v3));
            }
        } else if (OUTMODE == 1) {
            __half* op = (__half*)outp + ((size_t)((b * HH + yg) * WW + xg)) * 216;
#pragma unroll
            for (int mt = 0; mt < 4; ++mt) {
                int o = oc0 + mt * 16 + q * 4;
                if (o + 3 < 216) {
                    float v0 = acc[mt][nt][0] + bv[mt][0];
                    float v1 = acc[mt][nt][1] + bv[mt][1];
                    float v2 = acc[mt][nt][2] + bv[mt][2];
                    float v3 = acc[mt][nt][3] + bv[mt][3];
                    *(uint2*)(op + o) = make_uint2(pack2h(v0, v1), pack2h(v2, v3));
                }
            }
        } else {
            float* op = (float*)outp + ((size_t)(b * 64) * HH) * WW + yg * WW + xg;
#pragma unroll
            for (int mt = 0; mt < 4; ++mt)
#pragma unroll
                for (int r = 0; r < 4; ++r) {
                    int o = mt * 16 + q * 4 + r;
                    op[(size_t)o * PLANE] = lrelu(acc[mt][nt][r] + bv[mt][r]);
                }
        }
    }
}

// ---------------------------------------------------------------------------
// DCN v2 as MFMA implicit-GEMM. fea: NHWC fp16 [B][H][W][64];
// om: NHWC fp16 stride 216; wr: fp16 [18][64][32]; out: NHWC64 fp16 + lrelu.
// Per block: 16x16 px, 64 out-ch, 4 waves. K = 72 taps x 8 ch = 576,
// 18 chunks of 32 (4 taps). Each thread samples its own pixel's 4 taps per
// chunk (bilinear 8ch via one f16x8 load per corner), writes LDS col-buffer.
// grid = (8, 8, 2*B)
// ---------------------------------------------------------------------------
__global__ __launch_bounds__(256)
void dcn_mfma_kernel(const __half* __restrict__ fa, const __half* __restrict__ fb,
                     const __half* __restrict__ oma, const __half* __restrict__ omb,
                     const __half* __restrict__ wr, const float* __restrict__ bias,
                     __half* __restrict__ outa, __half* __restrict__ outb)
{
    const int tid  = threadIdx.x;
    const int lane = tid & 63;
    const int wv   = tid >> 6;
    const int p16  = lane & 15;
    const int q    = lane >> 4;
    const int job  = blockIdx.z >> 2;
    const int b    = blockIdx.z & 3;
    const int tx0  = blockIdx.x * 16;
    const int ty0  = blockIdx.y * 16;

    const __half* fea = job ? fb : fa;
    const __half* om  = job ? omb : oma;
    __half* out       = job ? outb : outa;

    const int xs = tx0 + (tid & 15);
    const int ys = ty0 + (tid >> 4);
    const __half* omp  = om + (size_t)((b * HH + ys) * WW + xs) * 216;
    const __half* feab = fea + (size_t)b * PLANE * 64;

    __shared__ __align__(16) __half colbuf[256 * 40];
    __shared__ __align__(16) __half wl[2][64 * 40];

    f32x4 acc[4][4];
#pragma unroll
    for (int mt = 0; mt < 4; ++mt)
#pragma unroll
        for (int nt = 0; nt < 4; ++nt)
            acc[mt][nt] = (f32x4)(0.f);

    const int wo  = tid >> 2;
    const int wqq = tid & 3;
    // stage chunk-0 weights
    *(uint4*)(&wl[0][wo * 40 + wqq * 8]) =
        *(const uint4*)(wr + (size_t)wo * 32 + wqq * 8);

#pragma unroll 1
    for (int cc = 0; cc < 18; ++cc) {
        // ---- sample 4 taps into col-buffer ----
#pragma unroll
        for (int tl = 0; tl < 4; ++tl) {
            int gk = cc * 4 + tl;
            int g  = gk / 9;
            int k2 = gk - g * 9;
            int kyi = k2 / 3, kxi = k2 - kyi * 3;

            float dyo = __half2float(omp[g * 18 + 2 * k2]);
            float dxo = __half2float(omp[g * 18 + 2 * k2 + 1]);
            float mk  = __half2float(omp[144 + g * 9 + k2]);
            mk = 1.f / (1.f + expf(-mk));

            float py = (float)(ys + kyi - 1) + dyo;
            float px = (float)(xs + kxi - 1) + dxo;
            float fy = floorf(py), fx = floorf(px);
            int   y0 = (int)fy,    x0 = (int)fx;
            float ly = py - fy,    lx = px - fx;
            int   y1 = y0 + 1,     x1 = x0 + 1;

            float vy0 = (y0 >= 0 && y0 < HH) ? 1.f : 0.f;
            float vy1 = (y1 >= 0 && y1 < HH) ? 1.f : 0.f;
            float vx0 = (x0 >= 0 && x0 < WW) ? 1.f : 0.f;
            float vx1 = (x1 >= 0 && x1 < WW) ? 1.f : 0.f;

            float w00 = (1.f - ly) * (1.f - lx) * vy0 * vx0 * mk;
            float w01 = (1.f - ly) * lx         * vy0 * vx1 * mk;
            float w10 = ly         * (1.f - lx) * vy1 * vx0 * mk;
            float w11 = ly         * lx         * vy1 * vx1 * mk;

            int cy0 = min(max(y0, 0), HH - 1);
            int cy1 = min(max(y1, 0), HH - 1);
            int cx0 = min(max(x0, 0), WW - 1);
            int cx1 = min(max(x1, 0), WW - 1);
            int gb = g * 8;
            f16x8 c00 = *(const f16x8*)(feab + (size_t)(cy0 * WW + cx0) * 64 + gb);
            f16x8 c01 = *(const f16x8*)(feab + (size_t)(cy0 * WW + cx1) * 64 + gb);
            f16x8 c10 = *(const f16x8*)(feab + (size_t)(cy1 * WW + cx0) * 64 + gb);
            f16x8 c11 = *(const f16x8*)(feab + (size_t)(cy1 * WW + cx1) * 64 + gb);

            f16x8 pv;
#pragma unroll
            for (int i = 0; i < 8; ++i) {
                float v = w00 * (float)c00[i] + w01 * (float)c01[i]
                        + w10 * (float)c10[i] + w11 * (float)c11[i];
                pv[i] = (_Float16)v;
            }
            *(f16x8*)(&colbuf[tid * 40 + tl * 8]) = pv;
        }
        // ---- prefetch next chunk weights ----
        if (cc < 17) {
            uint4 v = *(const uint4*)(wr + ((size_t)(cc + 1) * 64 + wo) * 32 + wqq * 8);
            *(uint4*)(&wl[(cc + 1) & 1][wo * 40 + wqq * 8]) = v;
        }
        __syncthreads();

        const __half* wcur = wl[cc & 1];
        f16x8 af[4];
#pragma unroll
        for (int mt = 0; mt < 4; ++mt)
            af[mt] = *(const f16x8*)(&wcur[(mt * 16 + p16) * 40 + q * 8]);
#pragma unroll
        for (int nt = 0; nt < 4; ++nt) {
            f16x8 bf = *(const f16x8*)(&colbuf[(wv * 64 + nt * 16 + p16) * 40 + q * 8]);
#pragma unroll
            for (int mt = 0; mt < 4; ++mt)
                acc[mt][nt] = __builtin_amdgcn_mfma_f32_16x16x32_f16(
                    af[mt], bf, acc[mt][nt], 0, 0, 0);
        }
        __syncthreads();
    }

    // ---- epilogue: bias + lrelu, NHWC64 fp16 ----
    const int xg = tx0 + p16;
#pragma unroll
    for (int nt = 0; nt < 4; ++nt) {
        int yg = ty0 + 4 * wv + nt;
        __half* op = out + ((size_t)((b * HH + yg) * WW + xg)) * 64;
#pragma unroll
        for (int mt = 0; mt < 4; ++mt) {
            int o = mt * 16 + q * 4;
            float v0 = lrelu(acc[mt][nt][0] + bias[o]);
            float v1 = lrelu(acc[mt][nt][1] + bias[o + 1]);
            float v2 = lrelu(acc[mt][nt][2] + bias[o + 2]);
            float v3 = lrelu(acc[mt][nt][3] + bias[o + 3]);
            *(uint2*)(op + o) = make_uint2(pack2h(v0, v1), pack2h(v2, v3));
        }
    }
}

// ---------------------------------------------------------------------------
extern "C" void kernel_launch(void* const* d_in, const int* in_sizes, int n_in,
                              void* d_out, int out_size, void* d_ws, size_t ws_size,
                              hipStream_t stream) {
    const float* fea   = (const float*)d_in[0];
    const float* ref   = (const float*)d_in[1];
    const float* w_of1 = (const float*)d_in[2];
    const float* b_of1 = (const float*)d_in[3];
    const float* w_of2 = (const float*)d_in[4];
    const float* b_of2 = (const float*)d_in[5];
    const float* w_or1 = (const float*)d_in[6];
    const float* b_or1 = (const float*)d_in[7];
    const float* w_or2 = (const float*)d_in[8];
    const float* b_or2 = (const float*)d_in[9];
    const float* w_om  = (const float*)d_in[10];
    const float* b_om  = (const float*)d_in[11];
    const float* w_dcn = (const float*)d_in[12];
    const float* b_dcn = (const float*)d_in[13];
    const float* w_fu1 = (const float*)d_in[14];
    const float* b_fu1 = (const float*)d_in[15];
    const float* w_fu2 = (const float*)d_in[16];
    const float* b_fu2 = (const float*)d_in[17];

    char* ws = (char*)d_ws;
    constexpr size_t SLOT = (size_t)BB * PLANE * 64 * 2;   //  8,388,608
    constexpr size_t OMSZ = (size_t)BB * PLANE * 216 * 2;  // 28,311,552
    __half* A0  = (__half*)(ws);
    __half* A1  = (__half*)(ws + SLOT);
    __half* A2  = (__half*)(ws + 2 * SLOT);
    __half* A3  = (__half*)(ws + 3 * SLOT);
    __half* A4  = (__half*)(ws + 4 * SLOT);
    char*   OMb0 = ws + 5 * SLOT;          // OMa region (41,943,040)
    char*   OMb1 = OMb0 + OMSZ;            // OMb region
    __half* OMa = (__half*)OMb0;
    __half* OMb = (__half*)OMb1;
    // W0..W3 overlay inside OMa (dead before om-conv writes OMa)
    __half* W0 = (__half*)(OMb0);              // of1a: 73728 h (147456 B)
    __half* W1 = (__half*)(OMb0 + 147456);     // of1b
    __half* W2 = (__half*)(OMb0 + 294912);     // of2a: 36864 h
    __half* W3 = (__half*)(OMb0 + 368640);     // of2b
    // persistent weights after both OM regions (total ws ~99.2 MB)
    char* WT = OMb1 + OMSZ;                    // 98,566,144
    __half* W4  = (__half*)(WT);               // om: 147456 h (294912 B)
    __half* W5  = (__half*)(WT + 294912);      // fu1: 73728 h
    __half* W6  = (__half*)(WT + 442368);      // fu2: 36864 h
    __half* W7h = (__half*)(WT + 516096);      // dcn fp16: 36864 h

    dim3 blk(256, 1, 1);

    convert_kernel<<<256, blk, 0, stream>>>(fea, A0);
    convert_kernel<<<256, blk, 0, stream>>>(ref, A1);
    repack_w16_kernel<<<288, blk, 0, stream>>>(w_of1, W0, 64, 128, 64);
    repack_w16_kernel<<<288, blk, 0, stream>>>(w_or1, W1, 64, 128, 64);
    repack_w16_kernel<<<144, blk, 0, stream>>>(w_of2, W2, 64, 64, 64);
    repack_w16_kernel<<<144, blk, 0, stream>>>(w_or2, W3, 64, 64, 64);
    repack_w16_kernel<<<576, blk, 0, stream>>>(w_om,  W4, 216, 64, 256);
    repack_w16_kernel<<<288, blk, 0, stream>>>(w_fu1, W5, 64, 128, 64);
    repack_w16_kernel<<<144, blk, 0, stream>>>(w_fu2, W6, 64, 64, 64);
    repack_dcn_w16_kernel<<<144, blk, 0, stream>>>(w_dcn, W7h);

    // of1 pair: [A0||A1] -> A2 ; [A1||A0] -> A3
    conv_mfma_kernel<4, 1, 0><<<dim3(8, 8, 8), blk, 0, stream>>>(
        A0, A1, A1, A0, W0, W1, b_of1, b_or1, A2, A3, 64);
    // of2b: A3 -> A4   (single job; frees A3 afterwards)
    conv_mfma_kernel<2, 1, 0><<<dim3(8, 8, 4), blk, 0, stream>>>(
        A3, A3, A3, A3, W3, W3, b_or2, b_or2, A4, A4, 64);
    // of2a: A2 -> A3
    conv_mfma_kernel<2, 1, 0><<<dim3(8, 8, 4), blk, 0, stream>>>(
        A2, A2, A2, A2, W2, W2, b_of2, b_of2, A3, A3, 64);
    // om pair: A3 -> OMa (job a), A4 -> OMb (job b); NHWC stride 216
    conv_mfma_kernel<2, 4, 1><<<dim3(8, 8, 32), blk, 0, stream>>>(
        A3, A3, A4, A4, W4, W4, b_om, b_om, OMa, OMb, 216);
    // dcn pair: (A0, OMa) -> A2 ; (A1, OMb) -> A3
    dcn_mfma_kernel<<<dim3(8, 8, 8), blk, 0, stream>>>(
        A0, A1, OMa, OMb, W7h, b_dcn, A2, A3);
    // fuse1: [A2||A3] -> A4
    conv_mfma_kernel<4, 1, 0><<<dim3(8, 8, 4), blk, 0, stream>>>(
        A2, A3, A2, A3, W5, W5, b_fu1, b_fu1, A4, A4, 64);
    // fuse2: A4 -> d_out (NCHW fp32 + lrelu)
    conv_mfma_kernel<2, 1, 2><<<dim3(8, 8, 4), blk, 0, stream>>>(
        A4, A4, A4, A4, W6, W6, b_fu2, b_fu2, d_out, d_out, 64);

    (void)in_sizes; (void)n_in; (void)out_size; (void)ws_size;
}